// Round 1
// baseline (5207.304 us; speedup 1.0000x reference)
//
#include <hip/hip_runtime.h>
#include <hip/hip_bf16.h>
#include <stdint.h>

typedef __attribute__((ext_vector_type(8))) short bf16x8;
typedef __attribute__((ext_vector_type(4))) float f32x4;
typedef unsigned short u16;

#define BB 64
#define SS 512
#define II 512
#define HH 1024
#define OO 512

// ---------- helpers ----------
__device__ __forceinline__ u16 f2bf(float f) {
  union { float f; unsigned u; } v; v.f = f;
  return (u16)((v.u + 0x7fffu + ((v.u >> 16) & 1u)) >> 16);
}
__device__ __forceinline__ float bf2f(u16 s) {
  union { float f; unsigned u; } v; v.u = ((unsigned)s) << 16;
  return v.f;
}
__device__ __forceinline__ void gload_lds16(const void* g, void* l) {
  __builtin_amdgcn_global_load_lds(
      (const __attribute__((address_space(1))) unsigned int*)g,
      (__attribute__((address_space(3))) unsigned int*)l, 16, 0, 0);
}

// ws layout (bytes)
#define U_OFF   ((size_t)0)                    // 512*64*1024 bf16 = 64 MiB
#define Z_OFF   ((size_t)67108864)             // 512*64*1024 bf16 = 64 MiB
#define WHB_OFF ((size_t)134217728)            // 1024*1024 bf16 = 2 MiB
#define WIB_OFF ((size_t)136314880)            // 1024*512 bf16 = 1 MiB
#define W3B_OFF ((size_t)137363456)            // 512*1024 bf16 = 1 MiB
#define HB_OFF  ((size_t)138412032)            // 2 * 64*1024 bf16 (ping-pong)
#define CNT_OFF ((size_t)(138412032 + 262144)) // 512 ints

// ---------- init: convert weights/h0 to bf16, zero z[0] and barrier counters ----------
__global__ void k_init(const float* __restrict__ Wi, const float* __restrict__ Wh,
                       const float* __restrict__ W3, const float* __restrict__ h0,
                       u16* __restrict__ Wib, u16* __restrict__ Whb, u16* __restrict__ W3b,
                       u16* __restrict__ hb, u16* __restrict__ z, int* __restrict__ cnt) {
  const int total = 524288 + 1048576 + 524288 + 65536 + 65536 + 512;
  int stride = gridDim.x * blockDim.x;
  for (int f = blockIdx.x * blockDim.x + threadIdx.x; f < total; f += stride) {
    int r = f;
    if (r < 524288)  { Wib[r] = f2bf(Wi[r]); continue; } r -= 524288;
    if (r < 1048576) { Whb[r] = f2bf(Wh[r]); continue; } r -= 1048576;
    if (r < 524288)  { W3b[r] = f2bf(W3[r]); continue; } r -= 524288;
    if (r < 65536)   { hb[r]  = f2bf(h0[r]); continue; } r -= 65536;
    if (r < 65536)   { z[r]   = 0;           continue; } r -= 65536;
    cnt[r] = 0;
  }
}

// ---------- P1: U[m, n] = x_row(m) @ Wi.T + bi, m=(t*64+b), bf16 out ----------
// 128x128 tile, BK=32, 4 waves (2x2), A reg-staged (fp32 x -> bf16 LDS), B via global_load_lds.
__global__ __launch_bounds__(256) void k_p1(const float* __restrict__ x,
                                            const u16* __restrict__ Wib,
                                            const float* __restrict__ bi,
                                            u16* __restrict__ U) {
  __shared__ u16 Asm[128 * 32];
  __shared__ u16 Bsm[128 * 32];
  const int tid = threadIdx.x, lane = tid & 63, w = tid >> 6;
  const int wm = w >> 1, wn = w & 1;
  const int tM = blockIdx.x * 128, tN = blockIdx.y * 128;

  const int ra = tid >> 1, ha = tid & 1;      // A staging: row, half
  const int am = tM + ra;
  const float* xrow = x + ((size_t)((am & 63) * SS + (am >> 6))) * II;
  const int brow_l = lane >> 2, bsl = lane & 3;

  f32x4 acc[4][4];
#pragma unroll
  for (int i = 0; i < 4; ++i)
#pragma unroll
    for (int j = 0; j < 4; ++j) acc[i][j] = (f32x4){0.f, 0.f, 0.f, 0.f};

  for (int ks = 0; ks < 16; ++ks) {
    const int k0 = ks * 32;
    __syncthreads();
    {  // A: 16 fp32 -> 2x bf16x8 ds_write_b128, slot-swizzled by (row&3)
      const float* src = xrow + k0 + ha * 16;
      f32x4 f0 = *(const f32x4*)(src);
      f32x4 f1 = *(const f32x4*)(src + 4);
      f32x4 f2 = *(const f32x4*)(src + 8);
      f32x4 f3 = *(const f32x4*)(src + 12);
      bf16x8 p0, p1;
#pragma unroll
      for (int i = 0; i < 4; ++i) { p0[i] = (short)f2bf(f0[i]); p0[4+i] = (short)f2bf(f1[i]); }
#pragma unroll
      for (int i = 0; i < 4; ++i) { p1[i] = (short)f2bf(f2[i]); p1[4+i] = (short)f2bf(f3[i]); }
      int s0 = (ha * 2) ^ (ra & 3), s1 = (ha * 2 + 1) ^ (ra & 3);
      *(bf16x8*)((char*)Asm + ra * 64 + s0 * 16) = p0;
      *(bf16x8*)((char*)Asm + ra * 64 + s1 * 16) = p1;
    }
#pragma unroll
    for (int q = 0; q < 2; ++q) {  // B: 2 global_load_lds calls per wave
      int call = w * 2 + q;
      int nr = call * 16 + brow_l;
      int sg = bsl ^ (nr & 3);
      gload_lds16(Wib + (size_t)(tN + nr) * II + k0 + sg * 8, (char*)Bsm + call * 1024);
    }
    __syncthreads();
    bf16x8 af[4], bfr[4];
#pragma unroll
    for (int fi = 0; fi < 4; ++fi) {
      int r = wm * 64 + fi * 16 + (lane & 15);
      int sl = (lane >> 4) ^ (r & 3);
      af[fi] = *(const bf16x8*)((const char*)Asm + r * 64 + sl * 16);
    }
#pragma unroll
    for (int fj = 0; fj < 4; ++fj) {
      int r = wn * 64 + fj * 16 + (lane & 15);
      int sl = (lane >> 4) ^ (r & 3);
      bfr[fj] = *(const bf16x8*)((const char*)Bsm + r * 64 + sl * 16);
    }
#pragma unroll
    for (int fi = 0; fi < 4; ++fi)
#pragma unroll
      for (int fj = 0; fj < 4; ++fj)
        acc[fi][fj] = __builtin_amdgcn_mfma_f32_16x16x32_bf16(af[fi], bfr[fj], acc[fi][fj], 0, 0, 0);
  }
  const int hi = lane >> 4, n15 = lane & 15;
#pragma unroll
  for (int fi = 0; fi < 4; ++fi)
#pragma unroll
    for (int fj = 0; fj < 4; ++fj) {
      int n = tN + wn * 64 + fj * 16 + n15;
      float bv = bi[n];
#pragma unroll
      for (int r4 = 0; r4 < 4; ++r4) {
        int m = tM + wm * 64 + fi * 16 + hi * 4 + r4;
        U[(size_t)m * HH + n] = f2bf(acc[fi][fj][r4] + bv);
      }
    }
}

// ---------- P2: persistent recurrence, 64 blocks (16 cols each), Wh slice in LDS ----------
__global__ __launch_bounds__(256, 1) void k_p2(const u16* __restrict__ U,
                                               const u16* __restrict__ Whb,
                                               const float* __restrict__ bh,
                                               u16* __restrict__ hbuf, u16* __restrict__ z,
                                               float* __restrict__ out_ht,
                                               int* __restrict__ cnt) {
  __shared__ u16 Wsm[16 * 1024];  // 32KB, XOR-swizzled by ((r&7)<<4)
  const int tid = threadIdx.x, lane = tid & 63, w = tid >> 6;
  const int j = blockIdx.x;
#pragma unroll
  for (int q = 0; q < 8; ++q) {   // stage Wh[j*16 .. +16][:] swizzled
    int u = tid * 8 + q;
    int r = u >> 7;
    int kb = (u & 127) * 16;
    bf16x8 v = *(const bf16x8*)(Whb + (size_t)(j * 16 + r) * HH + kb / 2);
    *(bf16x8*)((char*)Wsm + r * 2048 + (kb ^ ((r & 7) << 4))) = v;
  }
  const int n15 = lane & 15, hi = lane >> 4;
  const int ncol = j * 16 + n15;
  const float bhv = bh[ncol];
  const int mrow = w * 16 + hi * 4;      // C rows base (batch)
  const int arow = w * 16 + n15;         // A-frag row (batch)
  const int kcx = (n15 >> 2) & 1;        // bit6 of swizzle folded into kc
  const char* Bbase = (const char*)Wsm + n15 * 2048 + ((hi * 16) ^ ((n15 & 3) << 4));
  __syncthreads();

  for (int t = 0; t < 512; ++t) {
    const u16* hr = hbuf + ((t & 1) ? 65536 : 0) + (size_t)arow * HH + hi * 8;
    u16* hw = hbuf + ((t & 1) ? 0 : 65536);
    bf16x8 a[32];
#pragma unroll
    for (int kc = 0; kc < 32; ++kc) a[kc] = *(const bf16x8*)(hr + kc * 32);
    float uv[4];
    if (t <= 510) {
#pragma unroll
      for (int r = 0; r < 4; ++r)
        uv[r] = bf2f(U[((size_t)t * 64 + mrow + r) * HH + ncol]);
    }
    f32x4 acc = (f32x4){0.f, 0.f, 0.f, 0.f};
#pragma unroll
    for (int kc = 0; kc < 32; ++kc) {
      bf16x8 bfr = *(const bf16x8*)(Bbase + ((kc ^ kcx) << 6));
      acc = __builtin_amdgcn_mfma_f32_16x16x32_bf16(a[kc], bfr, acc, 0, 0, 0);
    }
#pragma unroll
    for (int r = 0; r < 4; ++r) {
      float g = acc[r] + bhv;                                 // g_t = h_t@Wh.T + bh
      if (t >= 1) z[((size_t)t * 64 + mrow + r) * HH + ncol] = f2bf(tanhf(g));
      if (t <= 510) {
        float hn = tanhf(uv[r] + g);                          // h_{t+1}
        hw[(size_t)(mrow + r) * HH + ncol] = f2bf(hn);
        if (t == 510) out_ht[(size_t)(mrow + r) * HH + ncol] = hn;
      }
    }
    if (t < 511) {  // device-scope grid barrier (64 blocks, all resident)
      __syncthreads();
      if (tid == 0) {
        __hip_atomic_fetch_add(&cnt[t], 1, __ATOMIC_RELEASE, __HIP_MEMORY_SCOPE_AGENT);
        while (__hip_atomic_load(&cnt[t], __ATOMIC_RELAXED, __HIP_MEMORY_SCOPE_AGENT) < 64)
          __builtin_amdgcn_s_sleep(1);
        __builtin_amdgcn_fence(__ATOMIC_ACQUIRE, "agent");
      }
      __syncthreads();
    }
  }
}

// ---------- P3: out = softmax(z @ W3.T + b3), 32x512 tile, fused softmax ----------
__global__ __launch_bounds__(256) void k_p3(const u16* __restrict__ z,
                                            const u16* __restrict__ W3b,
                                            const float* __restrict__ b3,
                                            float* __restrict__ out) {
  __shared__ u16 Asm[32 * 32];
  __shared__ u16 Bsm[512 * 32];
  __shared__ float redm[4][32];
  __shared__ float reds[4][32];
  const int tid = threadIdx.x, lane = tid & 63, w = tid >> 6;
  const int tM = blockIdx.x * 32;
  const int n15 = lane & 15, hi = lane >> 4;
  const int brow_l = lane >> 2, bsl = lane & 3;

  f32x4 acc[2][8];
#pragma unroll
  for (int mi = 0; mi < 2; ++mi)
#pragma unroll
    for (int nj = 0; nj < 8; ++nj) acc[mi][nj] = (f32x4){0.f, 0.f, 0.f, 0.f};
  float b3v[8];
#pragma unroll
  for (int nj = 0; nj < 8; ++nj) b3v[nj] = b3[w * 128 + nj * 16 + n15];

  for (int ks = 0; ks < 32; ++ks) {
    const int k0 = ks * 32;
    __syncthreads();
    if (w < 2) {  // A: z rows tM..tM+32
      int nr = w * 16 + brow_l;
      int sg = bsl ^ (nr & 3);
      gload_lds16(z + (size_t)(tM + nr) * HH + k0 + sg * 8, (char*)Asm + w * 1024);
    }
#pragma unroll
    for (int q = 0; q < 8; ++q) {  // B: all 512 W3 rows
      int call = w * 8 + q;
      int nr = call * 16 + brow_l;
      int sg = bsl ^ (nr & 3);
      gload_lds16(W3b + (size_t)nr * HH + k0 + sg * 8, (char*)Bsm + call * 1024);
    }
    __syncthreads();
    bf16x8 af[2], bfr[8];
#pragma unroll
    for (int mi = 0; mi < 2; ++mi) {
      int r = mi * 16 + n15;
      int sl = hi ^ (r & 3);
      af[mi] = *(const bf16x8*)((const char*)Asm + r * 64 + sl * 16);
    }
#pragma unroll
    for (int nj = 0; nj < 8; ++nj) {
      int r = w * 128 + nj * 16 + n15;
      int sl = hi ^ (r & 3);
      bfr[nj] = *(const bf16x8*)((const char*)Bsm + r * 64 + sl * 16);
    }
#pragma unroll
    for (int mi = 0; mi < 2; ++mi)
#pragma unroll
      for (int nj = 0; nj < 8; ++nj)
        acc[mi][nj] = __builtin_amdgcn_mfma_f32_16x16x32_bf16(af[mi], bfr[nj], acc[mi][nj], 0, 0, 0);
  }
  __syncthreads();
  // logits = acc + b3
#pragma unroll
  for (int mi = 0; mi < 2; ++mi)
#pragma unroll
    for (int nj = 0; nj < 8; ++nj)
#pragma unroll
      for (int r4 = 0; r4 < 4; ++r4) acc[mi][nj][r4] += b3v[nj];
  // row max: per-lane over nj, shuffle over n-phase lanes, LDS over waves
  float pm[2][4];
#pragma unroll
  for (int mi = 0; mi < 2; ++mi)
#pragma unroll
    for (int r4 = 0; r4 < 4; ++r4) {
      float m = -1e30f;
#pragma unroll
      for (int nj = 0; nj < 8; ++nj) m = fmaxf(m, acc[mi][nj][r4]);
      pm[mi][r4] = m;
    }
#pragma unroll
  for (int d = 1; d <= 8; d <<= 1)
#pragma unroll
    for (int mi = 0; mi < 2; ++mi)
#pragma unroll
      for (int r4 = 0; r4 < 4; ++r4)
        pm[mi][r4] = fmaxf(pm[mi][r4], __shfl_xor(pm[mi][r4], d));
  if (n15 == 0)
#pragma unroll
    for (int mi = 0; mi < 2; ++mi)
#pragma unroll
      for (int r4 = 0; r4 < 4; ++r4) redm[w][mi * 16 + hi * 4 + r4] = pm[mi][r4];
  __syncthreads();
  float rmax[2][4];
#pragma unroll
  for (int mi = 0; mi < 2; ++mi)
#pragma unroll
    for (int r4 = 0; r4 < 4; ++r4) {
      int row = mi * 16 + hi * 4 + r4;
      rmax[mi][r4] = fmaxf(fmaxf(redm[0][row], redm[1][row]), fmaxf(redm[2][row], redm[3][row]));
    }
  float rs[2][4];
#pragma unroll
  for (int mi = 0; mi < 2; ++mi)
#pragma unroll
    for (int r4 = 0; r4 < 4; ++r4) rs[mi][r4] = 0.f;
#pragma unroll
  for (int mi = 0; mi < 2; ++mi)
#pragma unroll
    for (int nj = 0; nj < 8; ++nj)
#pragma unroll
      for (int r4 = 0; r4 < 4; ++r4) {
        float e = __expf(acc[mi][nj][r4] - rmax[mi][r4]);
        acc[mi][nj][r4] = e;
        rs[mi][r4] += e;
      }
#pragma unroll
  for (int d = 1; d <= 8; d <<= 1)
#pragma unroll
    for (int mi = 0; mi < 2; ++mi)
#pragma unroll
      for (int r4 = 0; r4 < 4; ++r4) rs[mi][r4] += __shfl_xor(rs[mi][r4], d);
  if (n15 == 0)
#pragma unroll
    for (int mi = 0; mi < 2; ++mi)
#pragma unroll
      for (int r4 = 0; r4 < 4; ++r4) reds[w][mi * 16 + hi * 4 + r4] = rs[mi][r4];
  __syncthreads();
#pragma unroll
  for (int mi = 0; mi < 2; ++mi)
#pragma unroll
    for (int r4 = 0; r4 < 4; ++r4) {
      int row = mi * 16 + hi * 4 + r4;
      float s = reds[0][row] + reds[1][row] + reds[2][row] + reds[3][row];
      float inv = 1.f / s;
      int m = tM + row;
      int b = m & 63, tt = m >> 6;
      float* orow = out + ((size_t)b * SS + tt) * OO;
#pragma unroll
      for (int nj = 0; nj < 8; ++nj)
        orow[w * 128 + nj * 16 + n15] = acc[mi][nj][r4] * inv;
    }
}

extern "C" void kernel_launch(void* const* d_in, const int* in_sizes, int n_in,
                              void* d_out, int out_size, void* d_ws, size_t ws_size,
                              hipStream_t stream) {
  const float* x  = (const float*)d_in[0];
  const float* h0 = (const float*)d_in[1];
  const float* Wi = (const float*)d_in[2];
  const float* bi = (const float*)d_in[3];
  const float* Wh = (const float*)d_in[4];
  const float* bh = (const float*)d_in[5];
  const float* W3 = (const float*)d_in[6];
  const float* b3 = (const float*)d_in[7];
  float* out = (float*)d_out;
  float* out_ht = out + (size_t)BB * SS * OO;

  char* ws = (char*)d_ws;
  u16* U   = (u16*)(ws + U_OFF);
  u16* Z   = (u16*)(ws + Z_OFF);
  u16* Whb = (u16*)(ws + WHB_OFF);
  u16* Wib = (u16*)(ws + WIB_OFF);
  u16* W3b = (u16*)(ws + W3B_OFF);
  u16* HB  = (u16*)(ws + HB_OFF);
  int* CNT = (int*)(ws + CNT_OFF);

  hipLaunchKernelGGL(k_init, dim3(2048), dim3(256), 0, stream,
                     Wi, Wh, W3, h0, Wib, Whb, W3b, HB, Z, CNT);
  hipLaunchKernelGGL(k_p1, dim3(256, 8), dim3(256), 0, stream, x, Wib, bi, U);
  hipLaunchKernelGGL(k_p2, dim3(64), dim3(256), 0, stream, U, Whb, bh, HB, Z, out_ht, CNT);
  hipLaunchKernelGGL(k_p3, dim3(1024), dim3(256), 0, stream, Z, W3b, b3, out);
}

// Round 4
// 4571.619 us; speedup vs baseline: 1.1391x; 1.1391x over previous
//
#include <hip/hip_runtime.h>
#include <hip/hip_bf16.h>
#include <stdint.h>

typedef __attribute__((ext_vector_type(8))) short bf16x8;
typedef __attribute__((ext_vector_type(4))) float f32x4;
typedef unsigned short u16;

#define BB 64
#define SS 512
#define II 512
#define HH 1024
#define OO 512

// ---------- helpers ----------
__device__ __forceinline__ u16 f2bf(float f) {
  union { float f; unsigned u; } v; v.f = f;
  return (u16)((v.u + 0x7fffu + ((v.u >> 16) & 1u)) >> 16);
}
__device__ __forceinline__ float bf2f(u16 s) {
  union { float f; unsigned u; } v; v.u = ((unsigned)s) << 16;
  return v.f;
}
__device__ __forceinline__ void gload_lds16(const void* g, void* l) {
  __builtin_amdgcn_global_load_lds(
      (const __attribute__((address_space(1))) unsigned int*)g,
      (__attribute__((address_space(3))) unsigned int*)l, 16, 0, 0);
}

// ws layout (bytes)
#define U_OFF   ((size_t)0)                    // 512*64*1024 bf16 = 64 MiB
#define Z_OFF   ((size_t)67108864)             // 512*64*1024 bf16 = 64 MiB
#define WHB_OFF ((size_t)134217728)            // 1024*1024 bf16 = 2 MiB
#define WIB_OFF ((size_t)136314880)            // 1024*512 bf16 = 1 MiB
#define W3B_OFF ((size_t)137363456)            // 512*1024 bf16 = 1 MiB
#define HB_OFF  ((size_t)138412032)            // 2 * 64*1024 bf16 (ping-pong)
#define CNT_OFF ((size_t)(138412032 + 262144)) // 256 flags x 16 ints (64B padded)

// ---------- init: convert weights/h0 to bf16, zero z[0] and barrier flags ----------
__global__ void k_init(const float* __restrict__ Wi, const float* __restrict__ Wh,
                       const float* __restrict__ W3, const float* __restrict__ h0,
                       u16* __restrict__ Wib, u16* __restrict__ Whb, u16* __restrict__ W3b,
                       u16* __restrict__ hb, u16* __restrict__ z, int* __restrict__ cnt) {
  const int total = 524288 + 1048576 + 524288 + 65536 + 65536 + 4096;
  int stride = gridDim.x * blockDim.x;
  for (int f = blockIdx.x * blockDim.x + threadIdx.x; f < total; f += stride) {
    int r = f;
    if (r < 524288)  { Wib[r] = f2bf(Wi[r]); continue; } r -= 524288;
    if (r < 1048576) { Whb[r] = f2bf(Wh[r]); continue; } r -= 1048576;
    if (r < 524288)  { W3b[r] = f2bf(W3[r]); continue; } r -= 524288;
    if (r < 65536)   { hb[r]  = f2bf(h0[r]); continue; } r -= 65536;
    if (r < 65536)   { z[r]   = 0;           continue; } r -= 65536;
    cnt[r] = 0;
  }
}

// ---------- P1: U[m, n] = x_row(m) @ Wi.T + bi, m=(t*64+b), bf16 out ----------
__global__ __launch_bounds__(256) void k_p1(const float* __restrict__ x,
                                            const u16* __restrict__ Wib,
                                            const float* __restrict__ bi,
                                            u16* __restrict__ U) {
  __shared__ u16 Asm[128 * 32];
  __shared__ u16 Bsm[128 * 32];
  const int tid = threadIdx.x, lane = tid & 63, w = tid >> 6;
  const int wm = w >> 1, wn = w & 1;
  const int tM = blockIdx.x * 128, tN = blockIdx.y * 128;

  const int ra = tid >> 1, ha = tid & 1;
  const int am = tM + ra;
  const float* xrow = x + ((size_t)((am & 63) * SS + (am >> 6))) * II;
  const int brow_l = lane >> 2, bsl = lane & 3;

  f32x4 acc[4][4];
#pragma unroll
  for (int i = 0; i < 4; ++i)
#pragma unroll
    for (int j = 0; j < 4; ++j) acc[i][j] = (f32x4){0.f, 0.f, 0.f, 0.f};

  for (int ks = 0; ks < 16; ++ks) {
    const int k0 = ks * 32;
    __syncthreads();
    {
      const float* src = xrow + k0 + ha * 16;
      f32x4 f0 = *(const f32x4*)(src);
      f32x4 f1 = *(const f32x4*)(src + 4);
      f32x4 f2 = *(const f32x4*)(src + 8);
      f32x4 f3 = *(const f32x4*)(src + 12);
      bf16x8 p0, p1;
#pragma unroll
      for (int i = 0; i < 4; ++i) { p0[i] = (short)f2bf(f0[i]); p0[4+i] = (short)f2bf(f1[i]); }
#pragma unroll
      for (int i = 0; i < 4; ++i) { p1[i] = (short)f2bf(f2[i]); p1[4+i] = (short)f2bf(f3[i]); }
      int s0 = (ha * 2) ^ (ra & 3), s1 = (ha * 2 + 1) ^ (ra & 3);
      *(bf16x8*)((char*)Asm + ra * 64 + s0 * 16) = p0;
      *(bf16x8*)((char*)Asm + ra * 64 + s1 * 16) = p1;
    }
#pragma unroll
    for (int q = 0; q < 2; ++q) {
      int call = w * 2 + q;
      int nr = call * 16 + brow_l;
      int sg = bsl ^ (nr & 3);
      gload_lds16(Wib + (size_t)(tN + nr) * II + k0 + sg * 8, (char*)Bsm + call * 1024);
    }
    __syncthreads();
    bf16x8 af[4], bfr[4];
#pragma unroll
    for (int fi = 0; fi < 4; ++fi) {
      int r = wm * 64 + fi * 16 + (lane & 15);
      int sl = (lane >> 4) ^ (r & 3);
      af[fi] = *(const bf16x8*)((const char*)Asm + r * 64 + sl * 16);
    }
#pragma unroll
    for (int fj = 0; fj < 4; ++fj) {
      int r = wn * 64 + fj * 16 + (lane & 15);
      int sl = (lane >> 4) ^ (r & 3);
      bfr[fj] = *(const bf16x8*)((const char*)Bsm + r * 64 + sl * 16);
    }
#pragma unroll
    for (int fi = 0; fi < 4; ++fi)
#pragma unroll
      for (int fj = 0; fj < 4; ++fj)
        acc[fi][fj] = __builtin_amdgcn_mfma_f32_16x16x32_bf16(af[fi], bfr[fj], acc[fi][fj], 0, 0, 0);
  }
  const int hi = lane >> 4, n15 = lane & 15;
#pragma unroll
  for (int fi = 0; fi < 4; ++fi)
#pragma unroll
    for (int fj = 0; fj < 4; ++fj) {
      int n = tN + wn * 64 + fj * 16 + n15;
      float bv = bi[n];
#pragma unroll
      for (int r4 = 0; r4 < 4; ++r4) {
        int m = tM + wm * 64 + fi * 16 + hi * 4 + r4;
        U[(size_t)m * HH + n] = f2bf(acc[fi][fj][r4] + bv);
      }
    }
}

// ---------- P2: persistent recurrence ----------
// 256 single-wave blocks = 4 independent batch-groups (16 batches) x 64 col-blocks
// (16 cols). Per-group flag-array barrier; no __syncthreads anywhere (1 wave/block).
__global__ __launch_bounds__(64, 1) void k_p2(const u16* __restrict__ U,
                                              const u16* __restrict__ Whb,
                                              const float* __restrict__ bh,
                                              u16* __restrict__ hbuf, u16* __restrict__ z,
                                              float* __restrict__ out_ht,
                                              int* __restrict__ flags) {
  __shared__ u16 Wsm[16 * 1024];  // 32KB, XOR-swizzled by ((r&7)<<4)
  const int tid = threadIdx.x;           // lane, 0..63
  const int blk = blockIdx.x;
  const int bg = blk >> 6, j = blk & 63; // batch-group, column-block
#pragma unroll
  for (int q = 0; q < 32; ++q) {         // stage Wh[j*16 .. +16][:] swizzled
    int u = q * 64 + tid;                // 0..2047 16B-slots
    int r = u >> 7;
    int kb = (u & 127) * 16;
    bf16x8 v = *(const bf16x8*)(Whb + (size_t)(j * 16 + r) * HH + kb / 2);
    *(bf16x8*)((char*)Wsm + r * 2048 + (kb ^ ((r & 7) << 4))) = v;
  }
  const int n15 = tid & 15, hi = tid >> 4;
  const int ncol = j * 16 + n15;
  const float bhv = bh[ncol];
  const int crow = bg * 16 + hi * 4;     // C rows base (batch)
  const int arow = bg * 16 + n15;        // A-frag row (batch)
  const int kcx = (n15 >> 2) & 1;
  const char* Bbase = (const char*)Wsm + n15 * 2048 + ((hi * 16) ^ ((n15 & 3) << 4));
  int* myflag = flags + (size_t)blk * 16;
  const int fbase = bg * 64 * 16;

  float uv[4];
#pragma unroll
  for (int r = 0; r < 4; ++r) uv[r] = bf2f(U[(size_t)(crow + r) * HH + ncol]);  // t=0

  for (int t = 0; t < 512; ++t) {
    const u16* hr = hbuf + ((t & 1) ? 65536 : 0) + (size_t)arow * HH + hi * 8;
    u16* hw = hbuf + ((t & 1) ? 0 : 65536);
    bf16x8 a[32];
#pragma unroll
    for (int kc = 0; kc < 32; ++kc) a[kc] = *(const bf16x8*)(hr + kc * 32);
    f32x4 ac0 = (f32x4){0.f,0.f,0.f,0.f}, ac1 = (f32x4){0.f,0.f,0.f,0.f};
    f32x4 ac2 = (f32x4){0.f,0.f,0.f,0.f}, ac3 = (f32x4){0.f,0.f,0.f,0.f};
#pragma unroll
    for (int kc = 0; kc < 32; kc += 4) {
      ac0 = __builtin_amdgcn_mfma_f32_16x16x32_bf16(a[kc],   *(const bf16x8*)(Bbase + (((kc    ) ^ kcx) << 6)), ac0, 0, 0, 0);
      ac1 = __builtin_amdgcn_mfma_f32_16x16x32_bf16(a[kc+1], *(const bf16x8*)(Bbase + (((kc + 1) ^ kcx) << 6)), ac1, 0, 0, 0);
      ac2 = __builtin_amdgcn_mfma_f32_16x16x32_bf16(a[kc+2], *(const bf16x8*)(Bbase + (((kc + 2) ^ kcx) << 6)), ac2, 0, 0, 0);
      ac3 = __builtin_amdgcn_mfma_f32_16x16x32_bf16(a[kc+3], *(const bf16x8*)(Bbase + (((kc + 3) ^ kcx) << 6)), ac3, 0, 0, 0);
    }
    f32x4 acc = (ac0 + ac1) + (ac2 + ac3);
    float g[4];
#pragma unroll
    for (int r = 0; r < 4; ++r) g[r] = acc[r] + bhv;   // g_t = h_t@Wh.T + bh
    if (t <= 510) {
#pragma unroll
      for (int r = 0; r < 4; ++r) {
        float hn = tanhf(uv[r] + g[r]);                // h_{t+1}
        hw[(size_t)(crow + r) * HH + ncol] = f2bf(hn);
        if (t == 510) out_ht[(size_t)(crow + r) * HH + ncol] = hn;
      }
      // release: vmcnt-drains the whole wave's h-stores, then publishes
      if (tid == 0)
        __hip_atomic_store(myflag, t + 1, __ATOMIC_RELEASE, __HIP_MEMORY_SCOPE_AGENT);
    }
    // ---- off-critical-path work overlapped with the barrier ----
    if (t >= 1) {
#pragma unroll
      for (int r = 0; r < 4; ++r)
        z[((size_t)t * 64 + crow + r) * HH + ncol] = f2bf(tanhf(g[r]));  // z[t]=tanh(g_t)
    }
    if (t < 511) {
      const u16* Un = U + (size_t)(t + 1) * 64 * HH;
#pragma unroll
      for (int r = 0; r < 4; ++r) uv[r] = bf2f(Un[(size_t)(crow + r) * HH + ncol]);
      // poll own group's 64 flags, one per lane
      const int* pf = flags + fbase + tid * 16;
      while (true) {
        int v = __hip_atomic_load(pf, __ATOMIC_RELAXED, __HIP_MEMORY_SCOPE_AGENT);
        if (__all(v >= t + 1)) break;
        __builtin_amdgcn_s_sleep(1);
      }
      __builtin_amdgcn_fence(__ATOMIC_ACQUIRE, "agent");
    }
  }
}

// ---------- P3: out = softmax(z @ W3.T + b3), 32x512 tile, fused softmax ----------
__global__ __launch_bounds__(256) void k_p3(const u16* __restrict__ z,
                                            const u16* __restrict__ W3b,
                                            const float* __restrict__ b3,
                                            float* __restrict__ out) {
  __shared__ u16 Asm[32 * 32];
  __shared__ u16 Bsm[512 * 32];
  __shared__ float redm[4][32];
  __shared__ float reds[4][32];
  const int tid = threadIdx.x, lane = tid & 63, w = tid >> 6;
  const int tM = blockIdx.x * 32;
  const int n15 = lane & 15, hi = lane >> 4;
  const int brow_l = lane >> 2, bsl = lane & 3;

  f32x4 acc[2][8];
#pragma unroll
  for (int mi = 0; mi < 2; ++mi)
#pragma unroll
    for (int nj = 0; nj < 8; ++nj) acc[mi][nj] = (f32x4){0.f, 0.f, 0.f, 0.f};
  float b3v[8];
#pragma unroll
  for (int nj = 0; nj < 8; ++nj) b3v[nj] = b3[w * 128 + nj * 16 + n15];

  for (int ks = 0; ks < 32; ++ks) {
    const int k0 = ks * 32;
    __syncthreads();
    if (w < 2) {
      int nr = w * 16 + brow_l;
      int sg = bsl ^ (nr & 3);
      gload_lds16(z + (size_t)(tM + nr) * HH + k0 + sg * 8, (char*)Asm + w * 1024);
    }
#pragma unroll
    for (int q = 0; q < 8; ++q) {
      int call = w * 8 + q;
      int nr = call * 16 + brow_l;
      int sg = bsl ^ (nr & 3);
      gload_lds16(W3b + (size_t)nr * HH + k0 + sg * 8, (char*)Bsm + call * 1024);
    }
    __syncthreads();
    bf16x8 af[2], bfr[8];
#pragma unroll
    for (int mi = 0; mi < 2; ++mi) {
      int r = mi * 16 + n15;
      int sl = hi ^ (r & 3);
      af[mi] = *(const bf16x8*)((const char*)Asm + r * 64 + sl * 16);
    }
#pragma unroll
    for (int nj = 0; nj < 8; ++nj) {
      int r = w * 128 + nj * 16 + n15;
      int sl = hi ^ (r & 3);
      bfr[nj] = *(const bf16x8*)((const char*)Bsm + r * 64 + sl * 16);
    }
#pragma unroll
    for (int mi = 0; mi < 2; ++mi)
#pragma unroll
      for (int nj = 0; nj < 8; ++nj)
        acc[mi][nj] = __builtin_amdgcn_mfma_f32_16x16x32_bf16(af[mi], bfr[nj], acc[mi][nj], 0, 0, 0);
  }
  __syncthreads();
#pragma unroll
  for (int mi = 0; mi < 2; ++mi)
#pragma unroll
    for (int nj = 0; nj < 8; ++nj)
#pragma unroll
      for (int r4 = 0; r4 < 4; ++r4) acc[mi][nj][r4] += b3v[nj];
  float pm[2][4];
#pragma unroll
  for (int mi = 0; mi < 2; ++mi)
#pragma unroll
    for (int r4 = 0; r4 < 4; ++r4) {
      float m = -1e30f;
#pragma unroll
      for (int nj = 0; nj < 8; ++nj) m = fmaxf(m, acc[mi][nj][r4]);
      pm[mi][r4] = m;
    }
#pragma unroll
  for (int d = 1; d <= 8; d <<= 1)
#pragma unroll
    for (int mi = 0; mi < 2; ++mi)
#pragma unroll
      for (int r4 = 0; r4 < 4; ++r4)
        pm[mi][r4] = fmaxf(pm[mi][r4], __shfl_xor(pm[mi][r4], d));
  if (n15 == 0)
#pragma unroll
    for (int mi = 0; mi < 2; ++mi)
#pragma unroll
      for (int r4 = 0; r4 < 4; ++r4) redm[w][mi * 16 + hi * 4 + r4] = pm[mi][r4];
  __syncthreads();
  float rmax[2][4];
#pragma unroll
  for (int mi = 0; mi < 2; ++mi)
#pragma unroll
    for (int r4 = 0; r4 < 4; ++r4) {
      int row = mi * 16 + hi * 4 + r4;
      rmax[mi][r4] = fmaxf(fmaxf(redm[0][row], redm[1][row]), fmaxf(redm[2][row], redm[3][row]));
    }
  float rs[2][4];
#pragma unroll
  for (int mi = 0; mi < 2; ++mi)
#pragma unroll
    for (int r4 = 0; r4 < 4; ++r4) rs[mi][r4] = 0.f;
#pragma unroll
  for (int mi = 0; mi < 2; ++mi)
#pragma unroll
    for (int nj = 0; nj < 8; ++nj)
#pragma unroll
      for (int r4 = 0; r4 < 4; ++r4) {
        float e = __expf(acc[mi][nj][r4] - rmax[mi][r4]);
        acc[mi][nj][r4] = e;
        rs[mi][r4] += e;
      }
#pragma unroll
  for (int d = 1; d <= 8; d <<= 1)
#pragma unroll
    for (int mi = 0; mi < 2; ++mi)
#pragma unroll
      for (int r4 = 0; r4 < 4; ++r4) rs[mi][r4] += __shfl_xor(rs[mi][r4], d);
  if (n15 == 0)
#pragma unroll
    for (int mi = 0; mi < 2; ++mi)
#pragma unroll
      for (int r4 = 0; r4 < 4; ++r4) reds[w][mi * 16 + hi * 4 + r4] = rs[mi][r4];
  __syncthreads();
#pragma unroll
  for (int mi = 0; mi < 2; ++mi)
#pragma unroll
    for (int r4 = 0; r4 < 4; ++r4) {
      int row = mi * 16 + hi * 4 + r4;
      float s = reds[0][row] + reds[1][row] + reds[2][row] + reds[3][row];
      float inv = 1.f / s;
      int m = tM + row;
      int b = m & 63, tt = m >> 6;
      float* orow = out + ((size_t)b * SS + tt) * OO;
#pragma unroll
      for (int nj = 0; nj < 8; ++nj)
        orow[w * 128 + nj * 16 + n15] = acc[mi][nj][r4] * inv;
    }
}

extern "C" void kernel_launch(void* const* d_in, const int* in_sizes, int n_in,
                              void* d_out, int out_size, void* d_ws, size_t ws_size,
                              hipStream_t stream) {
  const float* x  = (const float*)d_in[0];
  const float* h0 = (const float*)d_in[1];
  const float* Wi = (const float*)d_in[2];
  const float* bi = (const float*)d_in[3];
  const float* Wh = (const float*)d_in[4];
  const float* bh = (const float*)d_in[5];
  const float* W3 = (const float*)d_in[6];
  const float* b3 = (const float*)d_in[7];
  float* out = (float*)d_out;
  float* out_ht = out + (size_t)BB * SS * OO;

  char* ws = (char*)d_ws;
  u16* U   = (u16*)(ws + U_OFF);
  u16* Z   = (u16*)(ws + Z_OFF);
  u16* Whb = (u16*)(ws + WHB_OFF);
  u16* Wib = (u16*)(ws + WIB_OFF);
  u16* W3b = (u16*)(ws + W3B_OFF);
  u16* HB  = (u16*)(ws + HB_OFF);
  int* FLG = (int*)(ws + CNT_OFF);

  hipLaunchKernelGGL(k_init, dim3(2048), dim3(256), 0, stream,
                     Wi, Wh, W3, h0, Wib, Whb, W3b, HB, Z, FLG);
  hipLaunchKernelGGL(k_p1, dim3(256, 8), dim3(256), 0, stream, x, Wib, bi, U);
  hipLaunchKernelGGL(k_p2, dim3(256), dim3(64), 0, stream, U, Whb, bh, HB, Z, out_ht, FLG);
  hipLaunchKernelGGL(k_p3, dim3(1024), dim3(256), 0, stream, Z, W3b, b3, out);
}